// Round 8
// baseline (706.099 us; speedup 1.0000x reference)
//
#include <hip/hip_runtime.h>
#include <hip/hip_cooperative_groups.h>
namespace cg = cooperative_groups;

#define D 128
typedef unsigned short u16;
constexpr int NW = 30000;
constexpr int NT = 2000;
constexpr int NDOC = 20000;

// ---- relation-local bucket geometry (round 5/6; HW-verified correct) ----
constexpr int CAPB = 1024;
constexpr int SSP  = 136;                   // Ssum LDS pitch (u16)
constexpr int NBK_WW = (NW + 31) / 32;      // 938
constexpr int NBK_WT = NT / 4;              // 500
constexpr int NBK_TT = (NT + 31) / 32;      // 63
constexpr int NBK_WD = (NDOC + 31) / 32;    // 625
constexpr int NBK_TD = (NDOC + 31) / 32;    // 625
constexpr int BUK_WW = 0;
constexpr int BUK_WT = BUK_WW + NBK_WW;     // 938
constexpr int BUK_TT = BUK_WT + NBK_WT;     // 1438
constexpr int BUK_WD = BUK_TT + NBK_TT;     // 1501
constexpr int BUK_TD = BUK_WD + NBK_WD;     // 2126
constexpr int NBUK   = BUK_TD + NBK_TD;     // 2751

constexpr int EPB  = 4096;                  // edges per partition unit
constexpr int NF2B = (NW * D / 4 + 255) / 256;  // 3750 f2b units
constexpr int NBM4 = (NT + 63) / 64;            // 32 units per topic matmul
constexpr int NZU  = (NBUK + 255) / 256;        // 11 cursor-zero units
constexpr int NCMB = (NT * D + 255) / 256;      // 1000 combine units
constexpr int U1 = NF2B + 4 * NBM4 + 3 + NZU;   // prep units
constexpr int U3 = NBK_WW + NBK_TT + NBK_TD;    // 1626
constexpr int U4 = NBK_WT + NBK_WD;             // 1125
constexpr int MAXGRID = 1024;

struct RelDesc { const int* src; const int* dst; const float* w;
                 int e0; int buk0; int shift; int mask; };
struct Rels { RelDesc r[5]; };

__device__ __forceinline__ int which_rel(const Rels& R, int e)
{
    if (e < R.r[1].e0) return 0;
    if (e < R.r[2].e0) return 1;
    if (e < R.r[3].e0) return 2;
    if (e < R.r[4].e0) return 3;
    return 4;
}

__device__ __forceinline__ float b2f(u16 h)
{
    return __uint_as_float(((unsigned)h) << 16);
}
__device__ __forceinline__ u16 f2b(float f)   // round-to-nearest-even
{
    unsigned u = __float_as_uint(f);
    return (u16)((u + 0x7FFF + ((u >> 16) & 1)) >> 16);
}

typedef short bf16x8 __attribute__((ext_vector_type(8)));
typedef float f32x4 __attribute__((ext_vector_type(4)));
constexpr int WPITCH = 136;

// ---------------------------------------------------------------------------
// Shared-memory structs (coop kernel uses the union: max = Wt 34816B)
// ---------------------------------------------------------------------------
struct BucketSmem {
    int2 st[CAPB];          // entries in CSR order
    u16  Ssum[32 * SSP];    // bf16 row sums
    float degL[32];
    float wsumL[32];
    int h2[32], exc[32], cnt[32];
};
struct PartSm { int hist[NBUK]; int baseL[NBUK]; };
union Smem {
    u16 Wt[D * WPITCH];
    BucketSmem bs;
    PartSm pt;
};

struct MM4 { const float* W[4]; float* P[4]; };

struct FP {
    const float *feat_word, *feat_topic;
    const float *effect, *bern_td, *bern_tt;
    Rels R;
    int Etot, npb;
    MM4 m4;
    const float *W_ww, *W_wt, *W_wd;
    const float *b_ww, *b_wt, *b_wd, *b_td, *b_tt;
    int* cur; int2* edataP;
    u16 *fw16, *hw16, *wtd16, *wtt16;
    u16 *Wtg_ww, *Wtg_wt, *Wtg_wd;
    u16* Sb2; float* degf2;
    float *h_word, *h_topic, *h_doc;
};

// ---------------------------------------------------------------------------
// MFMA helpers. Fragment layouts per HW-verified guide mappings.
// ---------------------------------------------------------------------------
__device__ __forceinline__ void stage_wt(
    const float* __restrict__ Wg, u16* Wt, int tid)
{
    for (int i = tid; i < D * D; i += 256) {
        int k = i >> 7, nn = i & 127;
        Wt[nn * WPITCH + k] = f2b(Wg[i]);
    }
}

__device__ __forceinline__ void mfma_tile_f32(
    const float* __restrict__ X, const u16* Wt, int arow, int n,
    int lanelo, int quad, f32x4 acc[8])
{
#pragma unroll
    for (int ct = 0; ct < 8; ++ct) {
        acc[ct][0] = 0.f; acc[ct][1] = 0.f; acc[ct][2] = 0.f; acc[ct][3] = 0.f;
    }
#pragma unroll
    for (int k0 = 0; k0 < 4; ++k0) {
        bf16x8 a;
        if (arow < n) {
            const float* ap = X + (size_t)arow * D + k0 * 32 + quad * 8;
            float4 a0 = *(const float4*)ap;
            float4 a1 = *(const float4*)(ap + 4);
            a[0] = (short)f2b(a0.x); a[1] = (short)f2b(a0.y);
            a[2] = (short)f2b(a0.z); a[3] = (short)f2b(a0.w);
            a[4] = (short)f2b(a1.x); a[5] = (short)f2b(a1.y);
            a[6] = (short)f2b(a1.z); a[7] = (short)f2b(a1.w);
        } else {
#pragma unroll
            for (int j = 0; j < 8; ++j) a[j] = 0;
        }
#pragma unroll
        for (int ct = 0; ct < 8; ++ct) {
            bf16x8 b = *(const bf16x8*)&Wt[(ct * 16 + lanelo) * WPITCH
                                           + k0 * 32 + quad * 8];
            acc[ct] = __builtin_amdgcn_mfma_f32_16x16x32_bf16(a, b, acc[ct], 0, 0, 0);
        }
    }
}

// Segmented reduction for one dst slot; 16 gathers in flight per lane.
__device__ __forceinline__ void reduce_one_lds(
    const u16* __restrict__ Xb, const int2* st,
    int start, int end, int dl, int lane, BucketSmem& s)
{
    int half = lane >> 5;
    int q = (lane & 31) * 4;
    float4 acc = make_float4(0.f, 0.f, 0.f, 0.f);
    float wacc = 0.f;
    int j = start;
    for (; j + 32 <= end; j += 32) {
        int2 ee[16];
        ushort4 vv[16];
#pragma unroll
        for (int t = 0; t < 16; ++t) ee[t] = st[j + 2 * t + half];
#pragma unroll
        for (int t = 0; t < 16; ++t)
            vv[t] = *(const ushort4*)(Xb + (size_t)(ee[t].x & 0x7FFF) * D + q);
#pragma unroll
        for (int t = 0; t < 16; ++t) {
            float w = __int_as_float(ee[t].y);
            acc.x = fmaf(w, b2f(vv[t].x), acc.x);
            acc.y = fmaf(w, b2f(vv[t].y), acc.y);
            acc.z = fmaf(w, b2f(vv[t].z), acc.z);
            acc.w = fmaf(w, b2f(vv[t].w), acc.w);
            wacc += w;
        }
    }
    if (j + 16 <= end) {
        int2 ee[8];
        ushort4 vv[8];
#pragma unroll
        for (int t = 0; t < 8; ++t) ee[t] = st[j + 2 * t + half];
#pragma unroll
        for (int t = 0; t < 8; ++t)
            vv[t] = *(const ushort4*)(Xb + (size_t)(ee[t].x & 0x7FFF) * D + q);
#pragma unroll
        for (int t = 0; t < 8; ++t) {
            float w = __int_as_float(ee[t].y);
            acc.x = fmaf(w, b2f(vv[t].x), acc.x);
            acc.y = fmaf(w, b2f(vv[t].y), acc.y);
            acc.z = fmaf(w, b2f(vv[t].z), acc.z);
            acc.w = fmaf(w, b2f(vv[t].w), acc.w);
            wacc += w;
        }
        j += 16;
    }
    if (j + 8 <= end) {
        int2 ee[4];
        ushort4 vv[4];
#pragma unroll
        for (int t = 0; t < 4; ++t) ee[t] = st[j + 2 * t + half];
#pragma unroll
        for (int t = 0; t < 4; ++t)
            vv[t] = *(const ushort4*)(Xb + (size_t)(ee[t].x & 0x7FFF) * D + q);
#pragma unroll
        for (int t = 0; t < 4; ++t) {
            float w = __int_as_float(ee[t].y);
            acc.x = fmaf(w, b2f(vv[t].x), acc.x);
            acc.y = fmaf(w, b2f(vv[t].y), acc.y);
            acc.z = fmaf(w, b2f(vv[t].z), acc.z);
            acc.w = fmaf(w, b2f(vv[t].w), acc.w);
            wacc += w;
        }
        j += 8;
    }
    if (j + 4 <= end) {
        int2 ea = st[j + half];
        int2 eb = st[j + 2 + half];
        ushort4 va = *(const ushort4*)(Xb + (size_t)(ea.x & 0x7FFF) * D + q);
        ushort4 vb = *(const ushort4*)(Xb + (size_t)(eb.x & 0x7FFF) * D + q);
        float wa = __int_as_float(ea.y);
        float wb = __int_as_float(eb.y);
        acc.x = fmaf(wa, b2f(va.x), acc.x); acc.y = fmaf(wa, b2f(va.y), acc.y);
        acc.z = fmaf(wa, b2f(va.z), acc.z); acc.w = fmaf(wa, b2f(va.w), acc.w);
        acc.x = fmaf(wb, b2f(vb.x), acc.x); acc.y = fmaf(wb, b2f(vb.y), acc.y);
        acc.z = fmaf(wb, b2f(vb.z), acc.z); acc.w = fmaf(wb, b2f(vb.w), acc.w);
        wacc += wa + wb;
        j += 4;
    }
    for (; j < end; j += 2) {
        int jj = j + half;
        int2 e = st[jj < end ? jj : (end - 1)];
        float w = (jj < end) ? __int_as_float(e.y) : 0.f;
        ushort4 v = *(const ushort4*)(Xb + (size_t)(e.x & 0x7FFF) * D + q);
        acc.x = fmaf(w, b2f(v.x), acc.x); acc.y = fmaf(w, b2f(v.y), acc.y);
        acc.z = fmaf(w, b2f(v.z), acc.z); acc.w = fmaf(w, b2f(v.w), acc.w);
        wacc += w;
    }
    acc.x += __shfl_xor(acc.x, 32);
    acc.y += __shfl_xor(acc.y, 32);
    acc.z += __shfl_xor(acc.z, 32);
    acc.w += __shfl_xor(acc.w, 32);
    wacc  += __shfl_xor(wacc, 32);
    if (half == 0) {
        ushort4 o;
        o.x = f2b(acc.x); o.y = f2b(acc.y); o.z = f2b(acc.z); o.w = f2b(acc.w);
        *(ushort4*)(s.Ssum + dl * SSP + q) = o;
    }
    if (lane == 0) {
        s.degL[dl] = (float)(end - start);
        s.wsumL[dl] = wacc;
    }
}

// Bucket entries -> registers, histogram 32 dlocs, scan, scatter into CSR
// order in st, then per-wave slot reduces.
__device__ __forceinline__ void bucket_reduce(
    const u16* __restrict__ X, const int* __restrict__ cur,
    const int2* __restrict__ edataP, int buk, int nsl, BucketSmem& s)
{
    int tid = threadIdx.x;
    int nE = min(cur[buk], CAPB);
    const int2* gsrc = edataP + (size_t)buk * CAPB;
    int2 ev[CAPB / 256];
#pragma unroll
    for (int t = 0; t < CAPB / 256; ++t) {
        int i = t * 256 + tid;
        if (i < nE) ev[t] = gsrc[i];
    }
    if (tid < 32) { s.h2[tid] = 0; s.cnt[tid] = 0; }
    __syncthreads();
#pragma unroll
    for (int t = 0; t < CAPB / 256; ++t) {
        int i = t * 256 + tid;
        if (i < nE) atomicAdd(&s.h2[(ev[t].x >> 15) & 31], 1);
    }
    __syncthreads();
    if (tid < 32) s.exc[tid] = s.h2[tid];
    __syncthreads();
    for (int off = 1; off < 32; off <<= 1) {
        int t = 0;
        if (tid < 32 && tid >= off) t = s.exc[tid - off];
        __syncthreads();
        if (tid < 32) s.exc[tid] += t;
        __syncthreads();
    }
    if (tid < 32) s.exc[tid] -= s.h2[tid];   // exclusive prefix
    __syncthreads();
#pragma unroll
    for (int t = 0; t < CAPB / 256; ++t) {
        int i = t * 256 + tid;
        if (i < nE) {
            int dl = (ev[t].x >> 15) & 31;
            int rk = atomicAdd(&s.cnt[dl], 1);
            s.st[s.exc[dl] + rk] = ev[t];
        }
    }
    __syncthreads();
    int wv = tid >> 6, lane = tid & 63;
    for (int dl = wv; dl < nsl; dl += 4) {
        int start = s.exc[dl];
        reduce_one_lds(X, s.st, start, start + s.h2[dl], dl, lane, s);
    }
}

// Fused projection over the bucket's row sums (B-fragments from global bf16
// W^T table). Y = (S@W + wsum*bias)/deg [+ T/degT], optional bf16 mirror Yb.
__device__ __forceinline__ void fused_mm(
    BucketSmem& s, const u16* __restrict__ Wtg, const float* __restrict__ bias,
    const u16* __restrict__ Tg, const float* __restrict__ degTg,
    float* __restrict__ Y, u16* __restrict__ Yb, int row0, int n, int tid)
{
    int wv = tid >> 6, lane = tid & 63;
    int lanelo = lane & 15, quad = lane >> 4;
    int rt = wv >> 1, ch = wv & 1;
    int arow = rt * 16 + lanelo;
    f32x4 acc[4];
#pragma unroll
    for (int c = 0; c < 4; ++c) {
        acc[c][0] = 0.f; acc[c][1] = 0.f; acc[c][2] = 0.f; acc[c][3] = 0.f;
    }
#pragma unroll
    for (int k0 = 0; k0 < 4; ++k0) {
        bf16x8 a;
        if (arow < n) {
            a = *(const bf16x8*)(s.Ssum + arow * SSP + k0 * 32 + quad * 8);
        } else {
#pragma unroll
            for (int j = 0; j < 8; ++j) a[j] = 0;
        }
#pragma unroll
        for (int c = 0; c < 4; ++c) {
            int ct = ch * 4 + c;
            bf16x8 b = *(const bf16x8*)(Wtg + (ct * 16 + lanelo) * D
                                        + k0 * 32 + quad * 8);
            acc[c] = __builtin_amdgcn_mfma_f32_16x16x32_bf16(a, b, acc[c], 0, 0, 0);
        }
    }
    int rbase = rt * 16 + quad * 4;
#pragma unroll
    for (int r = 0; r < 4; ++r) {
        int row = rbase + r;
        if (row >= n) continue;
        float dgv = s.degL[row];
        float wsv = s.wsumL[row];
        float dtv = degTg ? degTg[row] : 0.f;
#pragma unroll
        for (int c = 0; c < 4; ++c) {
            int ct = ch * 4 + c;
            int col = ct * 16 + lanelo;
            float y = acc[c][r];
            y = dgv > 0.f ? (y + wsv * bias[col]) / dgv : 0.f;
            if (Tg && dtv > 0.f) y += b2f(Tg[(size_t)row * D + col]) / dtv;
            Y[(size_t)(row0 + row) * D + col] = y;
            if (Yb) Yb[(size_t)(row0 + row) * D + col] = f2b(y);
        }
    }
}

// Coalesced dump of bucket sums + degrees to global (tt/td cross terms).
__device__ __forceinline__ void dump_smem(
    BucketSmem& s, u16* __restrict__ Sg, float* __restrict__ degg,
    int nsl, int tid)
{
    for (int i = tid; i < nsl * 32; i += 256) {
        int row = i >> 5, c4 = (i & 31) * 4;
        *(ushort4*)(Sg + (size_t)row * D + c4) =
            *(const ushort4*)(s.Ssum + row * SSP + c4);
    }
    if (tid < nsl) degg[tid] = s.degL[tid];
}

// ---------------------------------------------------------------------------
// Per-unit bodies shared by the cooperative and multi-dispatch paths.
// ---------------------------------------------------------------------------
__device__ __forceinline__ void p1_unit(const FP& p, int u, u16* Wt, int tid)
{
    if (u < NF2B) {
        int i = u * 256 + tid;
        if (i < NW * D / 4) {
            float4 v = ((const float4*)p.feat_word)[i];
            ushort4 o;
            o.x = f2b(v.x); o.y = f2b(v.y); o.z = f2b(v.z); o.w = f2b(v.w);
            ((ushort4*)p.fw16)[i] = o;
        }
    } else if (u < NF2B + 4 * NBM4) {
        int idx = u - NF2B;
        int which = idx / NBM4;
        int bx = idx % NBM4;
        stage_wt(p.m4.W[which], Wt, tid);
        __syncthreads();
        int wv = tid >> 6, lane = tid & 63;
        int lanelo = lane & 15, quad = lane >> 4;
        int rowbase = bx * 64 + wv * 16;
        f32x4 acc[8];
        mfma_tile_f32(p.feat_topic, Wt, rowbase + lanelo, NT, lanelo, quad, acc);
        float* Y = p.m4.P[which];
        int rbase = rowbase + quad * 4;
#pragma unroll
        for (int r = 0; r < 4; ++r) {
            int row = rbase + r;
            if (row >= NT) continue;
#pragma unroll
            for (int ct = 0; ct < 8; ++ct)
                Y[(size_t)row * D + ct * 16 + lanelo] = acc[ct][r];
        }
        __syncthreads();
    } else if (u < NF2B + 4 * NBM4 + 3) {
        int which = u - NF2B - 4 * NBM4;
        const float* Wg = which == 0 ? p.W_ww : which == 1 ? p.W_wt : p.W_wd;
        u16* Wd = which == 0 ? p.Wtg_ww : which == 1 ? p.Wtg_wt : p.Wtg_wd;
        stage_wt(Wg, Wt, tid);
        __syncthreads();
        for (int i = tid; i < D * D; i += 256) {
            int nrow = i >> 7, k = i & 127;
            Wd[i] = Wt[nrow * WPITCH + k];
        }
        __syncthreads();
    } else {
        int i = (u - NF2B - 4 * NBM4 - 3) * 256 + tid;
        if (i < NBUK) p.cur[i] = 0;
    }
}

__device__ __forceinline__ void p2_unit(const FP& p, int u, PartSm& pt, int tid)
{
    if (u < p.npb) {
        for (int i = tid; i < NBUK; i += 256) pt.hist[i] = 0;
        __syncthreads();
        int base_e = u * EPB;
        int bs[EPB / 256];
        int2 se[EPB / 256];
#pragma unroll
        for (int r = 0; r < EPB / 256; ++r) {
            int e = base_e + r * 256 + tid;
            if (e < p.Etot) {
                int k = which_rel(p.R, e);
                int le = e - p.R.r[k].e0;
                int s = p.R.r[k].src[le];
                int dd = p.R.r[k].dst[le];
                float w = p.R.r[k].w[le];
                int b = p.R.r[k].buk0 + (dd >> p.R.r[k].shift);
                int dloc = dd & p.R.r[k].mask;
                bs[r] = b;
                se[r] = make_int2(s | (dloc << 15), __float_as_int(w));
                atomicAdd(&pt.hist[b], 1);
            } else {
                bs[r] = -1;
            }
        }
        __syncthreads();
        for (int i = tid; i < NBUK; i += 256)
            pt.baseL[i] = pt.hist[i] ? atomicAdd(&p.cur[i], pt.hist[i]) : 0;
        __syncthreads();
        for (int i = tid; i < NBUK; i += 256) pt.hist[i] = 0;
        __syncthreads();
#pragma unroll
        for (int r = 0; r < EPB / 256; ++r) {
            int b = bs[r];
            if (b >= 0) {
                int rk = atomicAdd(&pt.hist[b], 1) + pt.baseL[b];
                if (rk < CAPB)
                    p.edataP[(size_t)b * CAPB + rk] = se[r];
            }
        }
        __syncthreads();
    } else {
        int i = (u - p.npb) * 256 + tid;
        if (i < NT * D) {
            int row = i >> 7;
            int col = i & (D - 1);
            float eff = p.effect[row];
            float causal = (eff != 0.f) ? 1.f : 0.f;
            float zero = (eff == 0.f) ? 1.f : 0.f;
            float rmtd = p.bern_td[row] * zero;
            float rmtt = p.bern_tt[row] * zero;
            float pc = p.m4.P[2][i];
            float pn = p.m4.P[3][i];
            p.wtd16[i] = f2b(p.m4.P[0][i] + p.b_td[col] + causal * pc - rmtd * pn);
            p.wtt16[i] = f2b(p.m4.P[1][i] + p.b_tt[col] + causal * pc - rmtt * pn);
        }
    }
}

__device__ __forceinline__ void p3_unit(const FP& p, int u, BucketSmem& bs, int tid)
{
    if (u < NBK_WW) {
        int w0 = u * 32;
        int nsl = min(32, NW - w0);
        bucket_reduce(p.fw16, p.cur, p.edataP, BUK_WW + u, nsl, bs);
        __syncthreads();
        fused_mm(bs, p.Wtg_ww, p.b_ww, nullptr, nullptr,
                 p.h_word, p.hw16, w0, nsl, tid);
        __syncthreads();
    } else if (u < NBK_WW + NBK_TT) {
        int i = u - NBK_WW;
        int t0 = i * 32;
        int nsl = min(32, NT - t0);
        bucket_reduce(p.wtt16, p.cur, p.edataP, BUK_TT + i, nsl, bs);
        __syncthreads();
        dump_smem(bs, p.Sb2 + (size_t)t0 * D, p.degf2 + t0, nsl, tid);
        __syncthreads();
    } else {
        int i = u - NBK_WW - NBK_TT;
        int d0 = i * 32;
        int nsl = min(32, NDOC - d0);
        bucket_reduce(p.wtd16, p.cur, p.edataP, BUK_TD + i, nsl, bs);
        __syncthreads();
        dump_smem(bs, p.Sb2 + (size_t)(NT + d0) * D, p.degf2 + NT + d0, nsl, tid);
        __syncthreads();
    }
}

__device__ __forceinline__ void p4_unit(const FP& p, int u, BucketSmem& bs, int tid)
{
    if (u < NBK_WT) {
        int t0 = u * 4;
        bucket_reduce(p.hw16, p.cur, p.edataP, BUK_WT + u, 4, bs);
        __syncthreads();
        fused_mm(bs, p.Wtg_wt, p.b_wt, p.Sb2 + (size_t)t0 * D,
                 p.degf2 + t0, p.h_topic, nullptr, t0, 4, tid);
        __syncthreads();
    } else {
        int i = u - NBK_WT;
        int d0 = i * 32;
        int nsl = min(32, NDOC - d0);
        bucket_reduce(p.hw16, p.cur, p.edataP, BUK_WD + i, nsl, bs);
        __syncthreads();
        fused_mm(bs, p.Wtg_wd, p.b_wd, p.Sb2 + (size_t)(NT + d0) * D,
                 p.degf2 + NT + d0, p.h_doc, nullptr, d0, nsl, tid);
        __syncthreads();
    }
}

// ---------------------------------------------------------------------------
// Path 1: single cooperative kernel (grid-size-agnostic grid-stride phases).
// ---------------------------------------------------------------------------
__global__ __launch_bounds__(256, 4) void fused_kernel(FP p)
{
    __shared__ Smem sm;
    cg::grid_group grid = cg::this_grid();
    int tid = threadIdx.x;
    const int nb = (int)gridDim.x;

    for (int u = blockIdx.x; u < U1; u += nb) p1_unit(p, u, sm.Wt, tid);
    __threadfence();
    grid.sync();

    const int U2 = p.npb + NCMB;
    for (int u = blockIdx.x; u < U2; u += nb) p2_unit(p, u, sm.pt, tid);
    __threadfence();
    grid.sync();

    for (int u = blockIdx.x; u < U3; u += nb) p3_unit(p, u, sm.bs, tid);
    __threadfence();
    grid.sync();

    for (int u = blockIdx.x; u < U4; u += nb) p4_unit(p, u, sm.bs, tid);
}

// ---------------------------------------------------------------------------
// Path 2 (fallback): proven round-5 four-dispatch pipeline.
// ---------------------------------------------------------------------------
__global__ __launch_bounds__(256) void prep_kernel(FP p)
{
    __shared__ u16 Wt[D * WPITCH];
    p1_unit(p, (int)blockIdx.x, Wt, threadIdx.x);
}

__global__ __launch_bounds__(256) void part_combine_kernel(FP p)
{
    __shared__ PartSm pt;
    p2_unit(p, (int)blockIdx.x, pt, threadIdx.x);
}

__global__ __launch_bounds__(256, 4) void phaseA_kernel(FP p)
{
    __shared__ BucketSmem bs;
    p3_unit(p, (int)blockIdx.x, bs, threadIdx.x);
}

__global__ __launch_bounds__(256, 4) void phaseB_kernel(FP p)
{
    __shared__ BucketSmem bs;
    p4_unit(p, (int)blockIdx.x, bs, threadIdx.x);
}

extern "C" void kernel_launch(void* const* d_in, const int* in_sizes, int n_in,
                              void* d_out, int out_size, void* d_ws, size_t ws_size,
                              hipStream_t stream)
{
    const float* feat_word  = (const float*)d_in[0];
    const float* feat_topic = (const float*)d_in[1];
    const float* effect     = (const float*)d_in[2];
    const float* bern_td    = (const float*)d_in[3];
    const float* bern_tt    = (const float*)d_in[4];
    const int*   src_ww = (const int*)d_in[5];
    const int*   dst_ww = (const int*)d_in[6];
    const float* w_ww   = (const float*)d_in[7];
    const int*   src_wt = (const int*)d_in[8];
    const int*   dst_wt = (const int*)d_in[9];
    const float* w_wt   = (const float*)d_in[10];
    const int*   src_wd = (const int*)d_in[11];
    const int*   dst_wd = (const int*)d_in[12];
    const float* w_wd   = (const float*)d_in[13];
    const int*   src_td = (const int*)d_in[14];
    const int*   dst_td = (const int*)d_in[15];
    const float* w_td   = (const float*)d_in[16];
    const int*   src_tt = (const int*)d_in[17];
    const int*   dst_tt = (const int*)d_in[18];
    const float* w_tt   = (const float*)d_in[19];
    const float* W_ww = (const float*)d_in[20];
    const float* b_ww = (const float*)d_in[21];
    const float* W_wt = (const float*)d_in[22];
    const float* b_wt = (const float*)d_in[23];
    const float* W_wd = (const float*)d_in[24];
    const float* b_wd = (const float*)d_in[25];
    const float* W_td = (const float*)d_in[26];
    const float* b_td = (const float*)d_in[27];
    const float* W_tt = (const float*)d_in[28];
    const float* b_tt = (const float*)d_in[29];
    const float* W_causal = (const float*)d_in[30];
    const float* W_noise  = (const float*)d_in[31];

    const int E_ww = in_sizes[5];
    const int E_wt = in_sizes[8];
    const int E_wd = in_sizes[11];
    const int E_td = in_sizes[14];
    const int E_tt = in_sizes[17];
    const int E_total = E_ww + E_wt + E_wd + E_td + E_tt;

    // ---- workspace layout (4-byte units; dedicated regions, NO overlays) ----
    float* ws = (float*)d_ws;
    u16*   Sb2   = (u16*)ws; ws += (long long)(NT + NDOC) * D / 2;
    float* degf2 = ws; ws += NT + NDOC;
    int*   cur   = (int*)ws; ws += NBUK;
    ws += ((size_t)(ws - (float*)d_ws) & 1);     // 8B align
    int2*  edataP = (int2*)ws; ws += (long long)2 * NBUK * CAPB;
    float* P_td  = ws; ws += (long long)NT * D;
    float* P_tt  = ws; ws += (long long)NT * D;
    float* Pc    = ws; ws += (long long)NT * D;
    float* Pn    = ws; ws += (long long)NT * D;
    u16*   fw16  = (u16*)ws;  ws += (long long)NW * D / 2;
    u16*   hw16  = (u16*)ws;  ws += (long long)NW * D / 2;
    u16*   wtd16 = (u16*)ws;  ws += (long long)NT * D / 2;
    u16*   wtt16 = (u16*)ws;  ws += (long long)NT * D / 2;
    u16*   Wtg_ww = (u16*)ws; ws += (long long)D * D / 2;
    u16*   Wtg_wt = (u16*)ws; ws += (long long)D * D / 2;
    u16*   Wtg_wd = (u16*)ws; ws += (long long)D * D / 2;

    float* h_word  = (float*)d_out;
    float* h_topic = h_word + (long long)NW * D;
    float* h_doc   = h_topic + (long long)NT * D;

    FP p;
    p.feat_word = feat_word; p.feat_topic = feat_topic;
    p.effect = effect; p.bern_td = bern_td; p.bern_tt = bern_tt;
    p.R.r[0] = { src_ww, dst_ww, w_ww, 0,                         BUK_WW, 5, 31 };
    p.R.r[1] = { src_wt, dst_wt, w_wt, E_ww,                      BUK_WT, 2, 3  };
    p.R.r[2] = { src_tt, dst_tt, w_tt, E_ww + E_wt,               BUK_TT, 5, 31 };
    p.R.r[3] = { src_wd, dst_wd, w_wd, E_ww + E_wt + E_tt,        BUK_WD, 5, 31 };
    p.R.r[4] = { src_td, dst_td, w_td, E_ww + E_wt + E_tt + E_wd, BUK_TD, 5, 31 };
    p.Etot = E_total;
    p.npb = (E_total + EPB - 1) / EPB;
    p.m4.W[0] = W_td; p.m4.W[1] = W_tt; p.m4.W[2] = W_causal; p.m4.W[3] = W_noise;
    p.m4.P[0] = P_td; p.m4.P[1] = P_tt; p.m4.P[2] = Pc;       p.m4.P[3] = Pn;
    p.W_ww = W_ww; p.W_wt = W_wt; p.W_wd = W_wd;
    p.b_ww = b_ww; p.b_wt = b_wt; p.b_wd = b_wd; p.b_td = b_td; p.b_tt = b_tt;
    p.cur = cur; p.edataP = edataP;
    p.fw16 = fw16; p.hw16 = hw16; p.wtd16 = wtd16; p.wtt16 = wtt16;
    p.Wtg_ww = Wtg_ww; p.Wtg_wt = Wtg_wt; p.Wtg_wd = Wtg_wd;
    p.Sb2 = Sb2; p.degf2 = degf2;
    p.h_word = h_word; p.h_topic = h_topic; p.h_doc = h_doc;

    // ---- try cooperative single-kernel path (occupancy-sized grid) ----
    bool coop_ok = false;
    int nbpc = 0;
    hipError_t oe = hipOccupancyMaxActiveBlocksPerMultiprocessor(
        &nbpc, reinterpret_cast<const void*>(fused_kernel), 256, 0);
    if (oe == hipSuccess && nbpc > 0) {
        int ncu = 256;
        int dev = 0;
        if (hipGetDevice(&dev) == hipSuccess)
            (void)hipDeviceGetAttribute(&ncu,
                hipDeviceAttributeMultiprocessorCount, dev);
        long long cap = (long long)nbpc * ncu;
        unsigned grid = (unsigned)(cap < MAXGRID ? cap : MAXGRID);
        if (grid >= 64) {
            void* args[] = { (void*)&p };
            hipError_t le = hipLaunchCooperativeKernel(
                (const void*)fused_kernel, dim3(grid), dim3(256), args, 0, stream);
            coop_ok = (le == hipSuccess);
        }
    }
    if (!coop_ok) {
        (void)hipGetLastError();   // clear any sticky error from failed attempt
        // ---- fallback: proven 4-dispatch pipeline (round-5 structure) ----
        prep_kernel<<<U1, 256, 0, stream>>>(p);
        part_combine_kernel<<<(unsigned)(p.npb + NCMB), 256, 0, stream>>>(p);
        phaseA_kernel<<<U3, 256, 0, stream>>>(p);
        phaseB_kernel<<<U4, 256, 0, stream>>>(p);
    }

    (void)n_in; (void)in_sizes; (void)out_size; (void)ws_size;
}

// Round 9
// 246.246 us; speedup vs baseline: 2.8675x; 2.8675x over previous
//
#include <hip/hip_runtime.h>

#define D 128
typedef unsigned short u16;
constexpr int NW = 30000;
constexpr int NT = 2000;
constexpr int NDOC = 20000;

// ---- relation-local bucket geometry (round 5/6; HW-verified correct) ----
constexpr int CAPB = 1024;
constexpr int SSP  = 136;                   // Ssum LDS pitch (u16)
constexpr int NBK_WW = (NW + 31) / 32;      // 938
constexpr int NBK_WT = NT / 4;              // 500
constexpr int NBK_TT = (NT + 31) / 32;      // 63
constexpr int NBK_WD = (NDOC + 31) / 32;    // 625
constexpr int NBK_TD = (NDOC + 31) / 32;    // 625
constexpr int BUK_WW = 0;
constexpr int BUK_WT = BUK_WW + NBK_WW;     // 938
constexpr int BUK_TT = BUK_WT + NBK_WT;     // 1438
constexpr int BUK_WD = BUK_TT + NBK_TT;     // 1501
constexpr int BUK_TD = BUK_WD + NBK_WD;     // 2126
constexpr int NBUK   = BUK_TD + NBK_TD;     // 2751

constexpr int EPB  = 4096;                  // edges per partition unit
constexpr int NF2B = (NW * D / 4 + 255) / 256;  // 3750 f2b units
constexpr int NMM4C = 32 * 4;               // 128 fused matmul+combine units
constexpr int NWTR  = 3 * 4;                // 12 W^T transpose-slice units
constexpr int U3 = NBK_WW + NBK_TT + NBK_TD;    // 1626
constexpr int U4 = NBK_WT + NBK_WD;             // 1125

struct RelDesc { const int* src; const int* dst; const float* w;
                 int e0; int buk0; int shift; int mask; };
struct Rels { RelDesc r[5]; };

__device__ __forceinline__ int which_rel(const Rels& R, int e)
{
    if (e < R.r[1].e0) return 0;
    if (e < R.r[2].e0) return 1;
    if (e < R.r[3].e0) return 2;
    if (e < R.r[4].e0) return 3;
    return 4;
}

__device__ __forceinline__ float b2f(u16 h)
{
    return __uint_as_float(((unsigned)h) << 16);
}
__device__ __forceinline__ u16 f2b(float f)   // round-to-nearest-even
{
    unsigned u = __float_as_uint(f);
    return (u16)((u + 0x7FFF + ((u >> 16) & 1)) >> 16);
}

typedef short bf16x8 __attribute__((ext_vector_type(8)));
typedef float f32x4 __attribute__((ext_vector_type(4)));
constexpr int WPITCH = 136;

// ---------------------------------------------------------------------------
// Shared-memory structs
// ---------------------------------------------------------------------------
struct BucketSmem {
    int2 st[CAPB];          // entries in CSR order
    u16  Ssum[32 * SSP];    // bf16 row sums
    float degL[32];
    float wsumL[32];
    int h2[32], exc[32], cnt[32];
};
struct PartSm { int hist[NBUK]; int baseL[NBUK]; };
union K1Sm {
    PartSm pt;              // 22008 B  (union max -> 7 blocks/CU)
    u16 Wts[32 * WPITCH];   // 8704 B, 32-col W slice
};

struct FP {
    const float *feat_word, *feat_topic;
    const float *effect, *bern_td, *bern_tt;
    Rels R;
    int Etot, npb;
    const float *W_td, *W_tt, *W_c, *W_n;
    const float *W_ww, *W_wt, *W_wd;
    const float *b_ww, *b_wt, *b_wd, *b_td, *b_tt;
    int* cur; int2* edataP;
    u16 *fw16, *hw16, *wtd16, *wtt16;
    u16 *Wtg_ww, *Wtg_wt, *Wtg_wd;
    u16* Sb2; float* degf2;
    float *h_word, *h_topic, *h_doc;
};

// ---------------------------------------------------------------------------
// MFMA helpers. Fragment layouts per HW-verified guide mappings:
// A[m=lane&15][k=quad*8+j], B[k][n=lane&15], C/D col=lane&15 row=quad*4+reg.
// ---------------------------------------------------------------------------
// Stage a 32-column slice of W: Wts[nl*WPITCH + k] = bf16(W[k][cs*32+nl])
__device__ __forceinline__ void mm_slice(
    const float* __restrict__ Wg, int cs, u16* Wts, int tid)
{
    for (int i = tid; i < 32 * D; i += 256) {
        int k = i >> 5, nl = i & 31;
        Wts[nl * WPITCH + k] = f2b(Wg[k * D + cs * 32 + nl]);
    }
}

// 16 rows x 32 cols MFMA over the staged slice, A-fragments preloaded.
__device__ __forceinline__ void mm_acc2(
    const bf16x8 a[4], const u16* Wts, int lanelo, int quad, f32x4 acc[2])
{
#pragma unroll
    for (int c = 0; c < 2; ++c) {
        acc[c][0] = 0.f; acc[c][1] = 0.f; acc[c][2] = 0.f; acc[c][3] = 0.f;
    }
#pragma unroll
    for (int k0 = 0; k0 < 4; ++k0) {
#pragma unroll
        for (int c = 0; c < 2; ++c) {
            bf16x8 b = *(const bf16x8*)&Wts[(c * 16 + lanelo) * WPITCH
                                            + k0 * 32 + quad * 8];
            acc[c] = __builtin_amdgcn_mfma_f32_16x16x32_bf16(a[k0], b, acc[c], 0, 0, 0);
        }
    }
}

// Segmented reduction for one dst slot (entries served from LDS).
__device__ __forceinline__ void reduce_one_lds(
    const u16* __restrict__ Xb, const int2* st,
    int start, int end, int dl, int lane, BucketSmem& s)
{
    int half = lane >> 5;
    int q = (lane & 31) * 4;
    float4 acc = make_float4(0.f, 0.f, 0.f, 0.f);
    float wacc = 0.f;
    int j = start;
    for (; j + 32 <= end; j += 32) {
        int2 ee[16];
        ushort4 vv[16];
#pragma unroll
        for (int t = 0; t < 16; ++t) ee[t] = st[j + 2 * t + half];
#pragma unroll
        for (int t = 0; t < 16; ++t)
            vv[t] = *(const ushort4*)(Xb + (size_t)(ee[t].x & 0x7FFF) * D + q);
#pragma unroll
        for (int t = 0; t < 16; ++t) {
            float w = __int_as_float(ee[t].y);
            acc.x = fmaf(w, b2f(vv[t].x), acc.x);
            acc.y = fmaf(w, b2f(vv[t].y), acc.y);
            acc.z = fmaf(w, b2f(vv[t].z), acc.z);
            acc.w = fmaf(w, b2f(vv[t].w), acc.w);
            wacc += w;
        }
    }
    if (j + 16 <= end) {
        int2 ee[8];
        ushort4 vv[8];
#pragma unroll
        for (int t = 0; t < 8; ++t) ee[t] = st[j + 2 * t + half];
#pragma unroll
        for (int t = 0; t < 8; ++t)
            vv[t] = *(const ushort4*)(Xb + (size_t)(ee[t].x & 0x7FFF) * D + q);
#pragma unroll
        for (int t = 0; t < 8; ++t) {
            float w = __int_as_float(ee[t].y);
            acc.x = fmaf(w, b2f(vv[t].x), acc.x);
            acc.y = fmaf(w, b2f(vv[t].y), acc.y);
            acc.z = fmaf(w, b2f(vv[t].z), acc.z);
            acc.w = fmaf(w, b2f(vv[t].w), acc.w);
            wacc += w;
        }
        j += 16;
    }
    if (j + 8 <= end) {
        int2 ee[4];
        ushort4 vv[4];
#pragma unroll
        for (int t = 0; t < 4; ++t) ee[t] = st[j + 2 * t + half];
#pragma unroll
        for (int t = 0; t < 4; ++t)
            vv[t] = *(const ushort4*)(Xb + (size_t)(ee[t].x & 0x7FFF) * D + q);
#pragma unroll
        for (int t = 0; t < 4; ++t) {
            float w = __int_as_float(ee[t].y);
            acc.x = fmaf(w, b2f(vv[t].x), acc.x);
            acc.y = fmaf(w, b2f(vv[t].y), acc.y);
            acc.z = fmaf(w, b2f(vv[t].z), acc.z);
            acc.w = fmaf(w, b2f(vv[t].w), acc.w);
            wacc += w;
        }
        j += 8;
    }
    if (j + 4 <= end) {
        int2 ea = st[j + half];
        int2 eb = st[j + 2 + half];
        ushort4 va = *(const ushort4*)(Xb + (size_t)(ea.x & 0x7FFF) * D + q);
        ushort4 vb = *(const ushort4*)(Xb + (size_t)(eb.x & 0x7FFF) * D + q);
        float wa = __int_as_float(ea.y);
        float wb = __int_as_float(eb.y);
        acc.x = fmaf(wa, b2f(va.x), acc.x); acc.y = fmaf(wa, b2f(va.y), acc.y);
        acc.z = fmaf(wa, b2f(va.z), acc.z); acc.w = fmaf(wa, b2f(va.w), acc.w);
        acc.x = fmaf(wb, b2f(vb.x), acc.x); acc.y = fmaf(wb, b2f(vb.y), acc.y);
        acc.z = fmaf(wb, b2f(vb.z), acc.z); acc.w = fmaf(wb, b2f(vb.w), acc.w);
        wacc += wa + wb;
        j += 4;
    }
    for (; j < end; j += 2) {
        int jj = j + half;
        int2 e = st[jj < end ? jj : (end - 1)];
        float w = (jj < end) ? __int_as_float(e.y) : 0.f;
        ushort4 v = *(const ushort4*)(Xb + (size_t)(e.x & 0x7FFF) * D + q);
        acc.x = fmaf(w, b2f(v.x), acc.x); acc.y = fmaf(w, b2f(v.y), acc.y);
        acc.z = fmaf(w, b2f(v.z), acc.z); acc.w = fmaf(w, b2f(v.w), acc.w);
        wacc += w;
    }
    acc.x += __shfl_xor(acc.x, 32);
    acc.y += __shfl_xor(acc.y, 32);
    acc.z += __shfl_xor(acc.z, 32);
    acc.w += __shfl_xor(acc.w, 32);
    wacc  += __shfl_xor(wacc, 32);
    if (half == 0) {
        ushort4 o;
        o.x = f2b(acc.x); o.y = f2b(acc.y); o.z = f2b(acc.z); o.w = f2b(acc.w);
        *(ushort4*)(s.Ssum + dl * SSP + q) = o;
    }
    if (lane == 0) {
        s.degL[dl] = (float)(end - start);
        s.wsumL[dl] = wacc;
    }
}

// Bucket entries -> registers, histogram 32 dlocs, scan, scatter into CSR
// order in st, then per-wave slot reduces.
__device__ __forceinline__ void bucket_reduce(
    const u16* __restrict__ X, const int* __restrict__ cur,
    const int2* __restrict__ edataP, int buk, int nsl, BucketSmem& s)
{
    int tid = threadIdx.x;
    int nE = min(cur[buk], CAPB);
    const int2* gsrc = edataP + (size_t)buk * CAPB;
    int2 ev[CAPB / 256];
#pragma unroll
    for (int t = 0; t < CAPB / 256; ++t) {
        int i = t * 256 + tid;
        if (i < nE) ev[t] = gsrc[i];
    }
    if (tid < 32) { s.h2[tid] = 0; s.cnt[tid] = 0; }
    __syncthreads();
#pragma unroll
    for (int t = 0; t < CAPB / 256; ++t) {
        int i = t * 256 + tid;
        if (i < nE) atomicAdd(&s.h2[(ev[t].x >> 15) & 31], 1);
    }
    __syncthreads();
    if (tid < 32) s.exc[tid] = s.h2[tid];
    __syncthreads();
    for (int off = 1; off < 32; off <<= 1) {
        int t = 0;
        if (tid < 32 && tid >= off) t = s.exc[tid - off];
        __syncthreads();
        if (tid < 32) s.exc[tid] += t;
        __syncthreads();
    }
    if (tid < 32) s.exc[tid] -= s.h2[tid];   // exclusive prefix
    __syncthreads();
#pragma unroll
    for (int t = 0; t < CAPB / 256; ++t) {
        int i = t * 256 + tid;
        if (i < nE) {
            int dl = (ev[t].x >> 15) & 31;
            int rk = atomicAdd(&s.cnt[dl], 1);
            s.st[s.exc[dl] + rk] = ev[t];
        }
    }
    __syncthreads();
    int wv = tid >> 6, lane = tid & 63;
    for (int dl = wv; dl < nsl; dl += 4) {
        int start = s.exc[dl];
        reduce_one_lds(X, s.st, start, start + s.h2[dl], dl, lane, s);
    }
}

// Fused projection over the bucket's row sums (B-fragments from global bf16
// W^T table). Y = (S@W + wsum*bias)/deg [+ T/degT], optional bf16 mirror Yb.
__device__ __forceinline__ void fused_mm(
    BucketSmem& s, const u16* __restrict__ Wtg, const float* __restrict__ bias,
    const u16* __restrict__ Tg, const float* __restrict__ degTg,
    float* __restrict__ Y, u16* __restrict__ Yb, int row0, int n, int tid)
{
    int wv = tid >> 6, lane = tid & 63;
    int lanelo = lane & 15, quad = lane >> 4;
    int rt = wv >> 1, ch = wv & 1;
    int arow = rt * 16 + lanelo;
    f32x4 acc[4];
#pragma unroll
    for (int c = 0; c < 4; ++c) {
        acc[c][0] = 0.f; acc[c][1] = 0.f; acc[c][2] = 0.f; acc[c][3] = 0.f;
    }
#pragma unroll
    for (int k0 = 0; k0 < 4; ++k0) {
        bf16x8 a;
        if (arow < n) {
            a = *(const bf16x8*)(s.Ssum + arow * SSP + k0 * 32 + quad * 8);
        } else {
#pragma unroll
            for (int j = 0; j < 8; ++j) a[j] = 0;
        }
#pragma unroll
        for (int c = 0; c < 4; ++c) {
            int ct = ch * 4 + c;
            bf16x8 b = *(const bf16x8*)(Wtg + (ct * 16 + lanelo) * D
                                        + k0 * 32 + quad * 8);
            acc[c] = __builtin_amdgcn_mfma_f32_16x16x32_bf16(a, b, acc[c], 0, 0, 0);
        }
    }
    int rbase = rt * 16 + quad * 4;
#pragma unroll
    for (int r = 0; r < 4; ++r) {
        int row = rbase + r;
        if (row >= n) continue;
        float dgv = s.degL[row];
        float wsv = s.wsumL[row];
        float dtv = degTg ? degTg[row] : 0.f;
#pragma unroll
        for (int c = 0; c < 4; ++c) {
            int ct = ch * 4 + c;
            int col = ct * 16 + lanelo;
            float y = acc[c][r];
            y = dgv > 0.f ? (y + wsv * bias[col]) / dgv : 0.f;
            if (Tg && dtv > 0.f) y += b2f(Tg[(size_t)row * D + col]) / dtv;
            Y[(size_t)(row0 + row) * D + col] = y;
            if (Yb) Yb[(size_t)(row0 + row) * D + col] = f2b(y);
        }
    }
}

// Coalesced dump of bucket sums + degrees to global (tt/td cross terms).
__device__ __forceinline__ void dump_smem(
    BucketSmem& s, u16* __restrict__ Sg, float* __restrict__ degg,
    int nsl, int tid)
{
    for (int i = tid; i < nsl * 32; i += 256) {
        int row = i >> 5, c4 = (i & 31) * 4;
        *(ushort4*)(Sg + (size_t)row * D + c4) =
            *(const ushort4*)(s.Ssum + row * SSP + c4);
    }
    if (tid < nsl) degg[tid] = s.degL[tid];
}

// ---------------------------------------------------------------------------
// Kernel 1: partition || f2b || fused 4-matmul+combine || W^T slices.
// All four unit families are mutually independent (cur pre-zeroed by
// hipMemsetAsync). Partition units placed first: they overlap with the
// BW-bound f2b and MFMA-bound matmul units on complementary pipes.
// ---------------------------------------------------------------------------
__global__ __launch_bounds__(256) void prep_part_kernel(FP p)
{
    __shared__ K1Sm sm;
    int tid = threadIdx.x;
    int u = (int)blockIdx.x;

    if (u < p.npb) {
        // ---- edge partition into relation-local bucket regions ----
        for (int i = tid; i < NBUK; i += 256) sm.pt.hist[i] = 0;
        __syncthreads();
        int base_e = u * EPB;
        int bs[EPB / 256];
        int2 se[EPB / 256];
#pragma unroll
        for (int r = 0; r < EPB / 256; ++r) {
            int e = base_e + r * 256 + tid;
            if (e < p.Etot) {
                int k = which_rel(p.R, e);
                int le = e - p.R.r[k].e0;
                int s = p.R.r[k].src[le];
                int dd = p.R.r[k].dst[le];
                float w = p.R.r[k].w[le];
                int b = p.R.r[k].buk0 + (dd >> p.R.r[k].shift);
                int dloc = dd & p.R.r[k].mask;
                bs[r] = b;
                se[r] = make_int2(s | (dloc << 15), __float_as_int(w));
                atomicAdd(&sm.pt.hist[b], 1);
            } else {
                bs[r] = -1;
            }
        }
        __syncthreads();
        for (int i = tid; i < NBUK; i += 256)
            sm.pt.baseL[i] = sm.pt.hist[i]
                ? atomicAdd(&p.cur[i], sm.pt.hist[i]) : 0;
        __syncthreads();
        for (int i = tid; i < NBUK; i += 256) sm.pt.hist[i] = 0;
        __syncthreads();
#pragma unroll
        for (int r = 0; r < EPB / 256; ++r) {
            int b = bs[r];
            if (b >= 0) {
                int rk = atomicAdd(&sm.pt.hist[b], 1) + sm.pt.baseL[b];
                if (rk < CAPB)
                    p.edataP[(size_t)b * CAPB + rk] = se[r];
            }
        }
    } else if (u < p.npb + NF2B) {
        // ---- feat_word fp32 -> bf16 ----
        int i = (u - p.npb) * 256 + tid;
        if (i < NW * D / 4) {
            float4 v = ((const float4*)p.feat_word)[i];
            ushort4 o;
            o.x = f2b(v.x); o.y = f2b(v.y); o.z = f2b(v.z); o.w = f2b(v.w);
            ((ushort4*)p.fw16)[i] = o;
        }
    } else if (u < p.npb + NF2B + NMM4C) {
        // ---- fused topic matmuls + combine: 64 rows x 32 cols per unit.
        // All 4 accumulators held in regs; wtd16/wtt16 written directly
        // (kills the P_* 16MB round trip and the separate combine pass).
        int idx = u - p.npb - NF2B;
        int rt = idx >> 2, cs = idx & 3;
        int wv = tid >> 6, lane = tid & 63;
        int lanelo = lane & 15, quad = lane >> 4;
        int arow = rt * 64 + wv * 16 + lanelo;
        bf16x8 a[4];
#pragma unroll
        for (int k0 = 0; k0 < 4; ++k0) {
            if (arow < NT) {
                const float* ap = p.feat_topic + (size_t)arow * D
                                  + k0 * 32 + quad * 8;
                float4 a0 = *(const float4*)ap;
                float4 a1 = *(const float4*)(ap + 4);
                a[k0][0] = (short)f2b(a0.x); a[k0][1] = (short)f2b(a0.y);
                a[k0][2] = (short)f2b(a0.z); a[k0][3] = (short)f2b(a0.w);
                a[k0][4] = (short)f2b(a1.x); a[k0][5] = (short)f2b(a1.y);
                a[k0][6] = (short)f2b(a1.z); a[k0][7] = (short)f2b(a1.w);
            } else {
#pragma unroll
                for (int j = 0; j < 8; ++j) a[k0][j] = 0;
            }
        }
        f32x4 aC[2], aN[2], aM[2];
        mm_slice(p.W_c, cs, sm.Wts, tid);  __syncthreads();
        mm_acc2(a, sm.Wts, lanelo, quad, aC); __syncthreads();
        mm_slice(p.W_n, cs, sm.Wts, tid);  __syncthreads();
        mm_acc2(a, sm.Wts, lanelo, quad, aN); __syncthreads();

        int rbase = rt * 64 + wv * 16 + quad * 4;
#pragma unroll
        for (int m = 0; m < 2; ++m) {
            const float* Wg   = m == 0 ? p.W_td : p.W_tt;
            const float* bias = m == 0 ? p.b_td : p.b_tt;
            const float* bern = m == 0 ? p.bern_td : p.bern_tt;
            u16* out = m == 0 ? p.wtd16 : p.wtt16;
            mm_slice(Wg, cs, sm.Wts, tid); __syncthreads();
            mm_acc2(a, sm.Wts, lanelo, quad, aM);
            float b0 = bias[cs * 32 + lanelo];
            float b1 = bias[cs * 32 + 16 + lanelo];
#pragma unroll
            for (int r = 0; r < 4; ++r) {
                int row = rbase + r;
                if (row >= NT) continue;
                float eff = p.effect[row];
                float causal = (eff != 0.f) ? 1.f : 0.f;
                float zero = (eff == 0.f) ? 1.f : 0.f;
                float rm = bern[row] * zero;
                float v0 = aM[0][r] + b0 + causal * aC[0][r] - rm * aN[0][r];
                float v1 = aM[1][r] + b1 + causal * aC[1][r] - rm * aN[1][r];
                out[(size_t)row * D + cs * 32 + lanelo] = f2b(v0);
                out[(size_t)row * D + cs * 32 + 16 + lanelo] = f2b(v1);
            }
            __syncthreads();
        }
    } else {
        // ---- W^T bf16 table slices (ww/wt/wd), via LDS transpose ----
        int idx = u - p.npb - NF2B - NMM4C;    // 0..11
        int which = idx >> 2, cs = idx & 3;
        const float* Wg = which == 0 ? p.W_ww : which == 1 ? p.W_wt : p.W_wd;
        u16* Wd = which == 0 ? p.Wtg_ww : which == 1 ? p.Wtg_wt : p.Wtg_wd;
        mm_slice(Wg, cs, sm.Wts, tid);
        __syncthreads();
        for (int i = tid; i < 32 * D; i += 256) {
            int nl = i >> 7, k = i & 127;
            Wd[(size_t)(cs * 32 + nl) * D + k] = sm.Wts[nl * WPITCH + k];
        }
    }
}

// ---------------------------------------------------------------------------
// Phase A: ww buckets (reduce + fused word projection -> h_word + hw16),
// tt/td buckets (reduce -> Sb2/degf2 cross terms).
// ---------------------------------------------------------------------------
__global__ __launch_bounds__(256, 4) void phaseA_kernel(FP p)
{
    __shared__ BucketSmem bs;
    int u = (int)blockIdx.x;
    int tid = threadIdx.x;
    if (u < NBK_WW) {
        int w0 = u * 32;
        int nsl = min(32, NW - w0);
        bucket_reduce(p.fw16, p.cur, p.edataP, BUK_WW + u, nsl, bs);
        __syncthreads();
        fused_mm(bs, p.Wtg_ww, p.b_ww, nullptr, nullptr,
                 p.h_word, p.hw16, w0, nsl, tid);
    } else if (u < NBK_WW + NBK_TT) {
        int i = u - NBK_WW;
        int t0 = i * 32;
        int nsl = min(32, NT - t0);
        bucket_reduce(p.wtt16, p.cur, p.edataP, BUK_TT + i, nsl, bs);
        __syncthreads();
        dump_smem(bs, p.Sb2 + (size_t)t0 * D, p.degf2 + t0, nsl, tid);
    } else {
        int i = u - NBK_WW - NBK_TT;
        int d0 = i * 32;
        int nsl = min(32, NDOC - d0);
        bucket_reduce(p.wtd16, p.cur, p.edataP, BUK_TD + i, nsl, bs);
        __syncthreads();
        dump_smem(bs, p.Sb2 + (size_t)(NT + d0) * D, p.degf2 + NT + d0, nsl, tid);
    }
}

// ---------------------------------------------------------------------------
// Phase B: wt/wd buckets (reduce + fused projections, + tt/td cross terms).
// ---------------------------------------------------------------------------
__global__ __launch_bounds__(256, 4) void phaseB_kernel(FP p)
{
    __shared__ BucketSmem bs;
    int u = (int)blockIdx.x;
    int tid = threadIdx.x;
    if (u < NBK_WT) {
        int t0 = u * 4;
        bucket_reduce(p.hw16, p.cur, p.edataP, BUK_WT + u, 4, bs);
        __syncthreads();
        fused_mm(bs, p.Wtg_wt, p.b_wt, p.Sb2 + (size_t)t0 * D,
                 p.degf2 + t0, p.h_topic, nullptr, t0, 4, tid);
    } else {
        int i = u - NBK_WT;
        int d0 = i * 32;
        int nsl = min(32, NDOC - d0);
        bucket_reduce(p.hw16, p.cur, p.edataP, BUK_WD + i, nsl, bs);
        __syncthreads();
        fused_mm(bs, p.Wtg_wd, p.b_wd, p.Sb2 + (size_t)(NT + d0) * D,
                 p.degf2 + NT + d0, p.h_doc, nullptr, d0, nsl, tid);
    }
}

extern "C" void kernel_launch(void* const* d_in, const int* in_sizes, int n_in,
                              void* d_out, int out_size, void* d_ws, size_t ws_size,
                              hipStream_t stream)
{
    const float* feat_word  = (const float*)d_in[0];
    const float* feat_topic = (const float*)d_in[1];
    const float* effect     = (const float*)d_in[2];
    const float* bern_td    = (const float*)d_in[3];
    const float* bern_tt    = (const float*)d_in[4];
    const int*   src_ww = (const int*)d_in[5];
    const int*   dst_ww = (const int*)d_in[6];
    const float* w_ww   = (const float*)d_in[7];
    const int*   src_wt = (const int*)d_in[8];
    const int*   dst_wt = (const int*)d_in[9];
    const float* w_wt   = (const float*)d_in[10];
    const int*   src_wd = (const int*)d_in[11];
    const int*   dst_wd = (const int*)d_in[12];
    const float* w_wd   = (const float*)d_in[13];
    const int*   src_td = (const int*)d_in[14];
    const int*   dst_td = (const int*)d_in[15];
    const float* w_td   = (const float*)d_in[16];
    const int*   src_tt = (const int*)d_in[17];
    const int*   dst_tt = (const int*)d_in[18];
    const float* w_tt   = (const float*)d_in[19];
    const float* W_ww = (const float*)d_in[20];
    const float* b_ww = (const float*)d_in[21];
    const float* W_wt = (const float*)d_in[22];
    const float* b_wt = (const float*)d_in[23];
    const float* W_wd = (const float*)d_in[24];
    const float* b_wd = (const float*)d_in[25];
    const float* W_td = (const float*)d_in[26];
    const float* b_td = (const float*)d_in[27];
    const float* W_tt = (const float*)d_in[28];
    const float* b_tt = (const float*)d_in[29];
    const float* W_causal = (const float*)d_in[30];
    const float* W_noise  = (const float*)d_in[31];

    const int E_ww = in_sizes[5];
    const int E_wt = in_sizes[8];
    const int E_wd = in_sizes[11];
    const int E_td = in_sizes[14];
    const int E_tt = in_sizes[17];
    const int E_total = E_ww + E_wt + E_wd + E_td + E_tt;

    // ---- workspace layout (4-byte units; dedicated regions, NO overlays) ----
    float* ws = (float*)d_ws;
    u16*   Sb2   = (u16*)ws; ws += (long long)(NT + NDOC) * D / 2;
    float* degf2 = ws; ws += NT + NDOC;
    int*   cur   = (int*)ws; ws += NBUK;
    ws += ((size_t)(ws - (float*)d_ws) & 1);     // 8B align
    int2*  edataP = (int2*)ws; ws += (long long)2 * NBUK * CAPB;
    u16*   fw16  = (u16*)ws;  ws += (long long)NW * D / 2;
    u16*   hw16  = (u16*)ws;  ws += (long long)NW * D / 2;
    u16*   wtd16 = (u16*)ws;  ws += (long long)NT * D / 2;
    u16*   wtt16 = (u16*)ws;  ws += (long long)NT * D / 2;
    u16*   Wtg_ww = (u16*)ws; ws += (long long)D * D / 2;
    u16*   Wtg_wt = (u16*)ws; ws += (long long)D * D / 2;
    u16*   Wtg_wd = (u16*)ws; ws += (long long)D * D / 2;

    float* h_word  = (float*)d_out;
    float* h_topic = h_word + (long long)NW * D;
    float* h_doc   = h_topic + (long long)NT * D;

    FP p;
    p.feat_word = feat_word; p.feat_topic = feat_topic;
    p.effect = effect; p.bern_td = bern_td; p.bern_tt = bern_tt;
    p.R.r[0] = { src_ww, dst_ww, w_ww, 0,                         BUK_WW, 5, 31 };
    p.R.r[1] = { src_wt, dst_wt, w_wt, E_ww,                      BUK_WT, 2, 3  };
    p.R.r[2] = { src_tt, dst_tt, w_tt, E_ww + E_wt,               BUK_TT, 5, 31 };
    p.R.r[3] = { src_wd, dst_wd, w_wd, E_ww + E_wt + E_tt,        BUK_WD, 5, 31 };
    p.R.r[4] = { src_td, dst_td, w_td, E_ww + E_wt + E_tt + E_wd, BUK_TD, 5, 31 };
    p.Etot = E_total;
    p.npb = (E_total + EPB - 1) / EPB;
    p.W_td = W_td; p.W_tt = W_tt; p.W_c = W_causal; p.W_n = W_noise;
    p.W_ww = W_ww; p.W_wt = W_wt; p.W_wd = W_wd;
    p.b_ww = b_ww; p.b_wt = b_wt; p.b_wd = b_wd; p.b_td = b_td; p.b_tt = b_tt;
    p.cur = cur; p.edataP = edataP;
    p.fw16 = fw16; p.hw16 = hw16; p.wtd16 = wtd16; p.wtt16 = wtt16;
    p.Wtg_ww = Wtg_ww; p.Wtg_wt = Wtg_wt; p.Wtg_wd = Wtg_wd;
    p.Sb2 = Sb2; p.degf2 = degf2;
    p.h_word = h_word; p.h_topic = h_topic; p.h_doc = h_doc;

    // cursor zeroing via async memset (capture-safe; removes the dependency
    // that forced partition to wait for a prep dispatch)
    hipMemsetAsync(cur, 0, NBUK * sizeof(int), stream);

    // ---- k1: partition || f2b || mm4+combine || W^T (all independent) ----
    unsigned g1 = (unsigned)(p.npb + NF2B + NMM4C + NWTR);
    prep_part_kernel<<<g1, 256, 0, stream>>>(p);

    // ---- k2: ww reduce+project, tt/td reduce+dump ----
    phaseA_kernel<<<U3, 256, 0, stream>>>(p);

    // ---- k3: wt/wd reduce+project (+ tt/td cross terms) ----
    phaseB_kernel<<<U4, 256, 0, stream>>>(p);

    (void)n_in; (void)in_sizes; (void)out_size; (void)ws_size;
}

// Round 10
// 244.501 us; speedup vs baseline: 2.8879x; 1.0071x over previous
//
#include <hip/hip_runtime.h>

#define D 128
typedef unsigned short u16;
constexpr int NW = 30000;
constexpr int NT = 2000;
constexpr int NDOC = 20000;

// ---- relation-local bucket geometry (partition side: 32-slot buckets) ----
constexpr int CAPB = 1024;
constexpr int SSP  = 136;                   // Ssum LDS pitch (u16)
constexpr int NBK_WW = (NW + 31) / 32;      // 938
constexpr int NBK_WT = NT / 4;              // 500
constexpr int NBK_TT = (NT + 31) / 32;      // 63
constexpr int NBK_WD = (NDOC + 31) / 32;    // 625
constexpr int NBK_TD = (NDOC + 31) / 32;    // 625
constexpr int BUK_WW = 0;
constexpr int BUK_WT = BUK_WW + NBK_WW;     // 938
constexpr int BUK_TT = BUK_WT + NBK_WT;     // 1438
constexpr int BUK_WD = BUK_TT + NBK_TT;     // 1501
constexpr int BUK_TD = BUK_WD + NBK_WD;     // 2126
constexpr int NBUK   = BUK_TD + NBK_TD;     // 2751

constexpr int EPB  = 4096;                  // edges per partition unit
constexpr int NF2B = (NW * D / 4 + 255) / 256;  // 3750 f2b units
constexpr int NMM4C = 32 * 4;               // 128 fused matmul+combine units
constexpr int NWTR  = 3 * 4;                // 12 W^T transpose-slice units
constexpr int U3 = NBK_WW + NBK_TT + NBK_TD;    // 1626 phaseA buckets
constexpr int U4 = NBK_WT + NBK_WD;             // 1125 phaseB buckets
// Reduce side: 2 blocks per bucket (16-slot halves). Sibling blocks are 8
// apart in blockIdx so XCD round-robin puts them on the SAME XCD (the
// duplicate bucket staging then L2-hits). Grid = ceil(U/8)*16.
constexpr int GA = ((U3 + 7) / 8) * 16;     // 3264
constexpr int GB = ((U4 + 7) / 8) * 16;     // 2256

struct RelDesc { const int* src; const int* dst; const float* w;
                 int e0; int buk0; int shift; int mask; };
struct Rels { RelDesc r[5]; };

__device__ __forceinline__ int which_rel(const Rels& R, int e)
{
    if (e < R.r[1].e0) return 0;
    if (e < R.r[2].e0) return 1;
    if (e < R.r[3].e0) return 2;
    if (e < R.r[4].e0) return 3;
    return 4;
}

__device__ __forceinline__ float b2f(u16 h)
{
    return __uint_as_float(((unsigned)h) << 16);
}
__device__ __forceinline__ u16 f2b(float f)   // round-to-nearest-even
{
    unsigned u = __float_as_uint(f);
    return (u16)((u + 0x7FFF + ((u >> 16) & 1)) >> 16);
}

typedef short bf16x8 __attribute__((ext_vector_type(8)));
typedef float f32x4 __attribute__((ext_vector_type(4)));
constexpr int WPITCH = 136;

// ---------------------------------------------------------------------------
// Shared-memory structs
// ---------------------------------------------------------------------------
struct BucketSmem {
    int2 st[CAPB];          // entries in CSR order (full bucket)
    u16  Ssum[16 * SSP];    // bf16 row sums (this block's 16-slot half, local)
    float degL[16];
    float wsumL[16];
    int h2[32], exc[32], cnt[32];
};
struct PartSm { int hist[NBUK]; int baseL[NBUK]; };
union K1Sm {
    PartSm pt;              // 22008 B
    u16 Wts[32 * WPITCH];   // 8704 B, 32-col W slice
};

struct FP {
    const float *feat_word, *feat_topic;
    const float *effect, *bern_td, *bern_tt;
    Rels R;
    int Etot, npb;
    const float *W_td, *W_tt, *W_c, *W_n;
    const float *W_ww, *W_wt, *W_wd;
    const float *b_ww, *b_wt, *b_wd, *b_td, *b_tt;
    int* cur; int2* edataP;
    u16 *fw16, *hw16, *wtd16, *wtt16;
    u16 *Wtg_ww, *Wtg_wt, *Wtg_wd;
    u16* Sb2; float* degf2;
    float *h_word, *h_topic, *h_doc;
};

// ---------------------------------------------------------------------------
// MFMA helpers. Fragment layouts per HW-verified guide mappings:
// A[m=lane&15][k=quad*8+j], B[k][n=lane&15], C/D col=lane&15 row=quad*4+reg.
// ---------------------------------------------------------------------------
__device__ __forceinline__ void mm_slice(
    const float* __restrict__ Wg, int cs, u16* Wts, int tid)
{
    for (int i = tid; i < 32 * D; i += 256) {
        int k = i >> 5, nl = i & 31;
        Wts[nl * WPITCH + k] = f2b(Wg[k * D + cs * 32 + nl]);
    }
}

__device__ __forceinline__ void mm_acc2(
    const bf16x8 a[4], const u16* Wts, int lanelo, int quad, f32x4 acc[2])
{
#pragma unroll
    for (int c = 0; c < 2; ++c) {
        acc[c][0] = 0.f; acc[c][1] = 0.f; acc[c][2] = 0.f; acc[c][3] = 0.f;
    }
#pragma unroll
    for (int k0 = 0; k0 < 4; ++k0) {
#pragma unroll
        for (int c = 0; c < 2; ++c) {
            bf16x8 b = *(const bf16x8*)&Wts[(c * 16 + lanelo) * WPITCH
                                            + k0 * 32 + quad * 8];
            acc[c] = __builtin_amdgcn_mfma_f32_16x16x32_bf16(a[k0], b, acc[c], 0, 0, 0);
        }
    }
}

// Segmented reduction for one dst slot (entries served from LDS). dl is the
// LOCAL slot index (0..15) within this block's half.
__device__ __forceinline__ void reduce_one_lds(
    const u16* __restrict__ Xb, const int2* st,
    int start, int end, int dl, int lane, BucketSmem& s)
{
    int half = lane >> 5;
    int q = (lane & 31) * 4;
    float4 acc = make_float4(0.f, 0.f, 0.f, 0.f);
    float wacc = 0.f;
    int j = start;
    for (; j + 32 <= end; j += 32) {
        int2 ee[16];
        ushort4 vv[16];
#pragma unroll
        for (int t = 0; t < 16; ++t) ee[t] = st[j + 2 * t + half];
#pragma unroll
        for (int t = 0; t < 16; ++t)
            vv[t] = *(const ushort4*)(Xb + (size_t)(ee[t].x & 0x7FFF) * D + q);
#pragma unroll
        for (int t = 0; t < 16; ++t) {
            float w = __int_as_float(ee[t].y);
            acc.x = fmaf(w, b2f(vv[t].x), acc.x);
            acc.y = fmaf(w, b2f(vv[t].y), acc.y);
            acc.z = fmaf(w, b2f(vv[t].z), acc.z);
            acc.w = fmaf(w, b2f(vv[t].w), acc.w);
            wacc += w;
        }
    }
    if (j + 16 <= end) {
        int2 ee[8];
        ushort4 vv[8];
#pragma unroll
        for (int t = 0; t < 8; ++t) ee[t] = st[j + 2 * t + half];
#pragma unroll
        for (int t = 0; t < 8; ++t)
            vv[t] = *(const ushort4*)(Xb + (size_t)(ee[t].x & 0x7FFF) * D + q);
#pragma unroll
        for (int t = 0; t < 8; ++t) {
            float w = __int_as_float(ee[t].y);
            acc.x = fmaf(w, b2f(vv[t].x), acc.x);
            acc.y = fmaf(w, b2f(vv[t].y), acc.y);
            acc.z = fmaf(w, b2f(vv[t].z), acc.z);
            acc.w = fmaf(w, b2f(vv[t].w), acc.w);
            wacc += w;
        }
        j += 16;
    }
    if (j + 8 <= end) {
        int2 ee[4];
        ushort4 vv[4];
#pragma unroll
        for (int t = 0; t < 4; ++t) ee[t] = st[j + 2 * t + half];
#pragma unroll
        for (int t = 0; t < 4; ++t)
            vv[t] = *(const ushort4*)(Xb + (size_t)(ee[t].x & 0x7FFF) * D + q);
#pragma unroll
        for (int t = 0; t < 4; ++t) {
            float w = __int_as_float(ee[t].y);
            acc.x = fmaf(w, b2f(vv[t].x), acc.x);
            acc.y = fmaf(w, b2f(vv[t].y), acc.y);
            acc.z = fmaf(w, b2f(vv[t].z), acc.z);
            acc.w = fmaf(w, b2f(vv[t].w), acc.w);
            wacc += w;
        }
        j += 8;
    }
    if (j + 4 <= end) {
        int2 ea = st[j + half];
        int2 eb = st[j + 2 + half];
        ushort4 va = *(const ushort4*)(Xb + (size_t)(ea.x & 0x7FFF) * D + q);
        ushort4 vb = *(const ushort4*)(Xb + (size_t)(eb.x & 0x7FFF) * D + q);
        float wa = __int_as_float(ea.y);
        float wb = __int_as_float(eb.y);
        acc.x = fmaf(wa, b2f(va.x), acc.x); acc.y = fmaf(wa, b2f(va.y), acc.y);
        acc.z = fmaf(wa, b2f(va.z), acc.z); acc.w = fmaf(wa, b2f(va.w), acc.w);
        acc.x = fmaf(wb, b2f(vb.x), acc.x); acc.y = fmaf(wb, b2f(vb.y), acc.y);
        acc.z = fmaf(wb, b2f(vb.z), acc.z); acc.w = fmaf(wb, b2f(vb.w), acc.w);
        wacc += wa + wb;
        j += 4;
    }
    for (; j < end; j += 2) {
        int jj = j + half;
        int2 e = st[jj < end ? jj : (end - 1)];
        float w = (jj < end) ? __int_as_float(e.y) : 0.f;
        ushort4 v = *(const ushort4*)(Xb + (size_t)(e.x & 0x7FFF) * D + q);
        acc.x = fmaf(w, b2f(v.x), acc.x); acc.y = fmaf(w, b2f(v.y), acc.y);
        acc.z = fmaf(w, b2f(v.z), acc.z); acc.w = fmaf(w, b2f(v.w), acc.w);
        wacc += w;
    }
    acc.x += __shfl_xor(acc.x, 32);
    acc.y += __shfl_xor(acc.y, 32);
    acc.z += __shfl_xor(acc.z, 32);
    acc.w += __shfl_xor(acc.w, 32);
    wacc  += __shfl_xor(wacc, 32);
    if (half == 0) {
        ushort4 o;
        o.x = f2b(acc.x); o.y = f2b(acc.y); o.z = f2b(acc.z); o.w = f2b(acc.w);
        *(ushort4*)(s.Ssum + dl * SSP + q) = o;
    }
    if (lane == 0) {
        s.degL[dl] = (float)(end - start);
        s.wsumL[dl] = wacc;
    }
}

// Stage FULL bucket -> regs -> CSR order in st (hist/scan over all 32 dlocs),
// then reduce ONLY slots [dl0, dl0+nslh) into local Ssum rows 0..nslh-1.
__device__ __forceinline__ void bucket_reduce_half(
    const u16* __restrict__ X, const int* __restrict__ cur,
    const int2* __restrict__ edataP, int buk, int dl0, int nslh, BucketSmem& s)
{
    int tid = threadIdx.x;
    int nE = min(cur[buk], CAPB);
    const int2* gsrc = edataP + (size_t)buk * CAPB;
    int2 ev[CAPB / 256];
#pragma unroll
    for (int t = 0; t < CAPB / 256; ++t) {
        int i = t * 256 + tid;
        if (i < nE) ev[t] = gsrc[i];
    }
    if (tid < 32) { s.h2[tid] = 0; s.cnt[tid] = 0; }
    __syncthreads();
#pragma unroll
    for (int t = 0; t < CAPB / 256; ++t) {
        int i = t * 256 + tid;
        if (i < nE) atomicAdd(&s.h2[(ev[t].x >> 15) & 31], 1);
    }
    __syncthreads();
    if (tid < 32) s.exc[tid] = s.h2[tid];
    __syncthreads();
    for (int off = 1; off < 32; off <<= 1) {
        int t = 0;
        if (tid < 32 && tid >= off) t = s.exc[tid - off];
        __syncthreads();
        if (tid < 32) s.exc[tid] += t;
        __syncthreads();
    }
    if (tid < 32) s.exc[tid] -= s.h2[tid];   // exclusive prefix
    __syncthreads();
#pragma unroll
    for (int t = 0; t < CAPB / 256; ++t) {
        int i = t * 256 + tid;
        if (i < nE) {
            int dl = (ev[t].x >> 15) & 31;
            int rk = atomicAdd(&s.cnt[dl], 1);
            s.st[s.exc[dl] + rk] = ev[t];
        }
    }
    __syncthreads();
    int wv = tid >> 6, lane = tid & 63;
    for (int dll = wv; dll < nslh; dll += 4) {
        int dl = dl0 + dll;
        int start = s.exc[dl];
        reduce_one_lds(X, s.st, start, start + s.h2[dl], dll, lane, s);
    }
}

// Fused projection over the half-bucket's 16 local rows. 4 waves x 2
// col-tiles (ct = wv*2+c). Tg/degTg are pre-offset to the half's base.
__device__ __forceinline__ void fused_mm16(
    BucketSmem& s, const u16* __restrict__ Wtg, const float* __restrict__ bias,
    const u16* __restrict__ Tg, const float* __restrict__ degTg,
    float* __restrict__ Y, u16* __restrict__ Yb, long long row0, int n, int tid)
{
    int wv = tid >> 6, lane = tid & 63;
    int lanelo = lane & 15, quad = lane >> 4;
    f32x4 acc[2];
#pragma unroll
    for (int c = 0; c < 2; ++c) {
        acc[c][0] = 0.f; acc[c][1] = 0.f; acc[c][2] = 0.f; acc[c][3] = 0.f;
    }
#pragma unroll
    for (int k0 = 0; k0 < 4; ++k0) {
        bf16x8 a;
        if (lanelo < n) {
            a = *(const bf16x8*)(s.Ssum + lanelo * SSP + k0 * 32 + quad * 8);
        } else {
#pragma unroll
            for (int j = 0; j < 8; ++j) a[j] = 0;
        }
#pragma unroll
        for (int c = 0; c < 2; ++c) {
            int ct = wv * 2 + c;
            bf16x8 b = *(const bf16x8*)(Wtg + (ct * 16 + lanelo) * D
                                        + k0 * 32 + quad * 8);
            acc[c] = __builtin_amdgcn_mfma_f32_16x16x32_bf16(a, b, acc[c], 0, 0, 0);
        }
    }
    int rbase = quad * 4;
#pragma unroll
    for (int r = 0; r < 4; ++r) {
        int row = rbase + r;           // local row
        if (row >= n) continue;
        float dgv = s.degL[row];
        float wsv = s.wsumL[row];
        float dtv = degTg ? degTg[row] : 0.f;
#pragma unroll
        for (int c = 0; c < 2; ++c) {
            int ct = wv * 2 + c;
            int col = ct * 16 + lanelo;
            float y = acc[c][r];
            y = dgv > 0.f ? (y + wsv * bias[col]) / dgv : 0.f;
            if (Tg && dtv > 0.f) y += b2f(Tg[(size_t)row * D + col]) / dtv;
            Y[(row0 + row) * D + col] = y;
            if (Yb) Yb[(row0 + row) * D + col] = f2b(y);
        }
    }
}

// Coalesced dump of the half's sums + degrees (tt/td cross terms). Sg/degg
// pre-offset to the half's global base; rows are local 0..nsl-1.
__device__ __forceinline__ void dump_smem16(
    BucketSmem& s, u16* __restrict__ Sg, float* __restrict__ degg,
    int nsl, int tid)
{
    for (int i = tid; i < nsl * 32; i += 256) {
        int row = i >> 5, c4 = (i & 31) * 4;
        *(ushort4*)(Sg + (size_t)row * D + c4) =
            *(const ushort4*)(s.Ssum + row * SSP + c4);
    }
    if (tid < nsl) degg[tid] = s.degL[tid];
}

// ---------------------------------------------------------------------------
// Kernel 1: partition || f2b || fused 4-matmul+combine || W^T slices.
// ---------------------------------------------------------------------------
__global__ __launch_bounds__(256) void prep_part_kernel(FP p)
{
    __shared__ K1Sm sm;
    int tid = threadIdx.x;
    int u = (int)blockIdx.x;

    if (u < p.npb) {
        // ---- edge partition into relation-local bucket regions ----
        for (int i = tid; i < NBUK; i += 256) sm.pt.hist[i] = 0;
        __syncthreads();
        int base_e = u * EPB;
        int bs[EPB / 256];
        int2 se[EPB / 256];
#pragma unroll
        for (int r = 0; r < EPB / 256; ++r) {
            int e = base_e + r * 256 + tid;
            if (e < p.Etot) {
                int k = which_rel(p.R, e);
                int le = e - p.R.r[k].e0;
                int s = p.R.r[k].src[le];
                int dd = p.R.r[k].dst[le];
                float w = p.R.r[k].w[le];
                int b = p.R.r[k].buk0 + (dd >> p.R.r[k].shift);
                int dloc = dd & p.R.r[k].mask;
                bs[r] = b;
                se[r] = make_int2(s | (dloc << 15), __float_as_int(w));
                atomicAdd(&sm.pt.hist[b], 1);
            } else {
                bs[r] = -1;
            }
        }
        __syncthreads();
        for (int i = tid; i < NBUK; i += 256)
            sm.pt.baseL[i] = sm.pt.hist[i]
                ? atomicAdd(&p.cur[i], sm.pt.hist[i]) : 0;
        __syncthreads();
        for (int i = tid; i < NBUK; i += 256) sm.pt.hist[i] = 0;
        __syncthreads();
#pragma unroll
        for (int r = 0; r < EPB / 256; ++r) {
            int b = bs[r];
            if (b >= 0) {
                int rk = atomicAdd(&sm.pt.hist[b], 1) + sm.pt.baseL[b];
                if (rk < CAPB)
                    p.edataP[(size_t)b * CAPB + rk] = se[r];
            }
        }
    } else if (u < p.npb + NF2B) {
        // ---- feat_word fp32 -> bf16 ----
        int i = (u - p.npb) * 256 + tid;
        if (i < NW * D / 4) {
            float4 v = ((const float4*)p.feat_word)[i];
            ushort4 o;
            o.x = f2b(v.x); o.y = f2b(v.y); o.z = f2b(v.z); o.w = f2b(v.w);
            ((ushort4*)p.fw16)[i] = o;
        }
    } else if (u < p.npb + NF2B + NMM4C) {
        // ---- fused topic matmuls + combine (wtd16/wtt16 direct) ----
        int idx = u - p.npb - NF2B;
        int rt = idx >> 2, cs = idx & 3;
        int wv = tid >> 6, lane = tid & 63;
        int lanelo = lane & 15, quad = lane >> 4;
        int arow = rt * 64 + wv * 16 + lanelo;
        bf16x8 a[4];
#pragma unroll
        for (int k0 = 0; k0 < 4; ++k0) {
            if (arow < NT) {
                const float* ap = p.feat_topic + (size_t)arow * D
                                  + k0 * 32 + quad * 8;
                float4 a0 = *(const float4*)ap;
                float4 a1 = *(const float4*)(ap + 4);
                a[k0][0] = (short)f2b(a0.x); a[k0][1] = (short)f2b(a0.y);
                a[k0][2] = (short)f2b(a0.z); a[k0][3] = (short)f2b(a0.w);
                a[k0][4] = (short)f2b(a1.x); a[k0][5] = (short)f2b(a1.y);
                a[k0][6] = (short)f2b(a1.z); a[k0][7] = (short)f2b(a1.w);
            } else {
#pragma unroll
                for (int j = 0; j < 8; ++j) a[k0][j] = 0;
            }
        }
        f32x4 aC[2], aN[2], aM[2];
        mm_slice(p.W_c, cs, sm.Wts, tid);  __syncthreads();
        mm_acc2(a, sm.Wts, lanelo, quad, aC); __syncthreads();
        mm_slice(p.W_n, cs, sm.Wts, tid);  __syncthreads();
        mm_acc2(a, sm.Wts, lanelo, quad, aN); __syncthreads();

        int rbase = rt * 64 + wv * 16 + quad * 4;
#pragma unroll
        for (int m = 0; m < 2; ++m) {
            const float* Wg   = m == 0 ? p.W_td : p.W_tt;
            const float* bias = m == 0 ? p.b_td : p.b_tt;
            const float* bern = m == 0 ? p.bern_td : p.bern_tt;
            u16* out = m == 0 ? p.wtd16 : p.wtt16;
            mm_slice(Wg, cs, sm.Wts, tid); __syncthreads();
            mm_acc2(a, sm.Wts, lanelo, quad, aM);
            float b0 = bias[cs * 32 + lanelo];
            float b1 = bias[cs * 32 + 16 + lanelo];
#pragma unroll
            for (int r = 0; r < 4; ++r) {
                int row = rbase + r;
                if (row >= NT) continue;
                float eff = p.effect[row];
                float causal = (eff != 0.f) ? 1.f : 0.f;
                float zero = (eff == 0.f) ? 1.f : 0.f;
                float rm = bern[row] * zero;
                float v0 = aM[0][r] + b0 + causal * aC[0][r] - rm * aN[0][r];
                float v1 = aM[1][r] + b1 + causal * aC[1][r] - rm * aN[1][r];
                out[(size_t)row * D + cs * 32 + lanelo] = f2b(v0);
                out[(size_t)row * D + cs * 32 + 16 + lanelo] = f2b(v1);
            }
            __syncthreads();
        }
    } else {
        // ---- W^T bf16 table slices (ww/wt/wd), via LDS transpose ----
        int idx = u - p.npb - NF2B - NMM4C;    // 0..11
        int which = idx >> 2, cs = idx & 3;
        const float* Wg = which == 0 ? p.W_ww : which == 1 ? p.W_wt : p.W_wd;
        u16* Wd = which == 0 ? p.Wtg_ww : which == 1 ? p.Wtg_wt : p.Wtg_wd;
        mm_slice(Wg, cs, sm.Wts, tid);
        __syncthreads();
        for (int i = tid; i < 32 * D; i += 256) {
            int nl = i >> 7, k = i & 127;
            Wd[(size_t)(cs * 32 + nl) * D + k] = sm.Wts[nl * WPITCH + k];
        }
    }
}

// ---------------------------------------------------------------------------
// Phase A: ww half-buckets (reduce + fused word projection -> h_word + hw16),
// tt/td half-buckets (reduce -> Sb2/degf2 cross terms).
// Sibling mapping: blocks b and b+8 process halves of the same bucket.
// ---------------------------------------------------------------------------
__global__ __launch_bounds__(256, 4) void phaseA_kernel(FP p)
{
    __shared__ BucketSmem bs;
    int b = (int)blockIdx.x;
    int u = ((b >> 4) << 3) | (b & 7);
    int h = (b >> 3) & 1;
    int tid = threadIdx.x;
    if (u >= U3) return;
    if (u < NBK_WW) {
        long long w0 = (long long)u * 32 + h * 16;
        int nslh = min(16, NW - (int)w0);
        if (nslh <= 0) return;
        bucket_reduce_half(p.fw16, p.cur, p.edataP, BUK_WW + u, h * 16, nslh, bs);
        __syncthreads();
        fused_mm16(bs, p.Wtg_ww, p.b_ww, nullptr, nullptr,
                   p.h_word, p.hw16, w0, nslh, tid);
    } else if (u < NBK_WW + NBK_TT) {
        int i = u - NBK_WW;
        int t0 = i * 32 + h * 16;
        int nslh = min(16, NT - t0);
        if (nslh <= 0) return;
        bucket_reduce_half(p.wtt16, p.cur, p.edataP, BUK_TT + i, h * 16, nslh, bs);
        __syncthreads();
        dump_smem16(bs, p.Sb2 + (size_t)t0 * D, p.degf2 + t0, nslh, tid);
    } else {
        int i = u - NBK_WW - NBK_TT;
        int d0 = i * 32 + h * 16;
        int nslh = min(16, NDOC - d0);
        if (nslh <= 0) return;
        bucket_reduce_half(p.wtd16, p.cur, p.edataP, BUK_TD + i, h * 16, nslh, bs);
        __syncthreads();
        dump_smem16(bs, p.Sb2 + (size_t)(NT + d0) * D, p.degf2 + NT + d0,
                    nslh, tid);
    }
}

// ---------------------------------------------------------------------------
// Phase B: wt half-buckets (2 slots) + wd half-buckets (16 slots), fused
// projections with tt/td cross terms. Gather from hw16.
// ---------------------------------------------------------------------------
__global__ __launch_bounds__(256, 4) void phaseB_kernel(FP p)
{
    __shared__ BucketSmem bs;
    int b = (int)blockIdx.x;
    int u = ((b >> 4) << 3) | (b & 7);
    int h = (b >> 3) & 1;
    int tid = threadIdx.x;
    if (u >= U4) return;
    if (u < NBK_WT) {
        int t0 = u * 4 + h * 2;
        bucket_reduce_half(p.hw16, p.cur, p.edataP, BUK_WT + u, h * 2, 2, bs);
        __syncthreads();
        fused_mm16(bs, p.Wtg_wt, p.b_wt, p.Sb2 + (size_t)t0 * D,
                   p.degf2 + t0, p.h_topic, nullptr, t0, 2, tid);
    } else {
        int i = u - NBK_WT;
        int d0 = i * 32 + h * 16;
        bucket_reduce_half(p.hw16, p.cur, p.edataP, BUK_WD + i, h * 16, 16, bs);
        __syncthreads();
        fused_mm16(bs, p.Wtg_wd, p.b_wd, p.Sb2 + (size_t)(NT + d0) * D,
                   p.degf2 + NT + d0, p.h_doc, nullptr, d0, 16, tid);
    }
}

extern "C" void kernel_launch(void* const* d_in, const int* in_sizes, int n_in,
                              void* d_out, int out_size, void* d_ws, size_t ws_size,
                              hipStream_t stream)
{
    const float* feat_word  = (const float*)d_in[0];
    const float* feat_topic = (const float*)d_in[1];
    const float* effect     = (const float*)d_in[2];
    const float* bern_td    = (const float*)d_in[3];
    const float* bern_tt    = (const float*)d_in[4];
    const int*   src_ww = (const int*)d_in[5];
    const int*   dst_ww = (const int*)d_in[6];
    const float* w_ww   = (const float*)d_in[7];
    const int*   src_wt = (const int*)d_in[8];
    const int*   dst_wt = (const int*)d_in[9];
    const float* w_wt   = (const float*)d_in[10];
    const int*   src_wd = (const int*)d_in[11];
    const int*   dst_wd = (const int*)d_in[12];
    const float* w_wd   = (const float*)d_in[13];
    const int*   src_td = (const int*)d_in[14];
    const int*   dst_td = (const int*)d_in[15];
    const float* w_td   = (const float*)d_in[16];
    const int*   src_tt = (const int*)d_in[17];
    const int*   dst_tt = (const int*)d_in[18];
    const float* w_tt   = (const float*)d_in[19];
    const float* W_ww = (const float*)d_in[20];
    const float* b_ww = (const float*)d_in[21];
    const float* W_wt = (const float*)d_in[22];
    const float* b_wt = (const float*)d_in[23];
    const float* W_wd = (const float*)d_in[24];
    const float* b_wd = (const float*)d_in[25];
    const float* W_td = (const float*)d_in[26];
    const float* b_td = (const float*)d_in[27];
    const float* W_tt = (const float*)d_in[28];
    const float* b_tt = (const float*)d_in[29];
    const float* W_causal = (const float*)d_in[30];
    const float* W_noise  = (const float*)d_in[31];

    const int E_ww = in_sizes[5];
    const int E_wt = in_sizes[8];
    const int E_wd = in_sizes[11];
    const int E_td = in_sizes[14];
    const int E_tt = in_sizes[17];
    const int E_total = E_ww + E_wt + E_wd + E_td + E_tt;

    // ---- workspace layout (4-byte units; dedicated regions, NO overlays) ----
    float* ws = (float*)d_ws;
    u16*   Sb2   = (u16*)ws; ws += (long long)(NT + NDOC) * D / 2;
    float* degf2 = ws; ws += NT + NDOC;
    int*   cur   = (int*)ws; ws += NBUK;
    ws += ((size_t)(ws - (float*)d_ws) & 1);     // 8B align
    int2*  edataP = (int2*)ws; ws += (long long)2 * NBUK * CAPB;
    u16*   fw16  = (u16*)ws;  ws += (long long)NW * D / 2;
    u16*   hw16  = (u16*)ws;  ws += (long long)NW * D / 2;
    u16*   wtd16 = (u16*)ws;  ws += (long long)NT * D / 2;
    u16*   wtt16 = (u16*)ws;  ws += (long long)NT * D / 2;
    u16*   Wtg_ww = (u16*)ws; ws += (long long)D * D / 2;
    u16*   Wtg_wt = (u16*)ws; ws += (long long)D * D / 2;
    u16*   Wtg_wd = (u16*)ws; ws += (long long)D * D / 2;

    float* h_word  = (float*)d_out;
    float* h_topic = h_word + (long long)NW * D;
    float* h_doc   = h_topic + (long long)NT * D;

    FP p;
    p.feat_word = feat_word; p.feat_topic = feat_topic;
    p.effect = effect; p.bern_td = bern_td; p.bern_tt = bern_tt;
    p.R.r[0] = { src_ww, dst_ww, w_ww, 0,                         BUK_WW, 5, 31 };
    p.R.r[1] = { src_wt, dst_wt, w_wt, E_ww,                      BUK_WT, 2, 3  };
    p.R.r[2] = { src_tt, dst_tt, w_tt, E_ww + E_wt,               BUK_TT, 5, 31 };
    p.R.r[3] = { src_wd, dst_wd, w_wd, E_ww + E_wt + E_tt,        BUK_WD, 5, 31 };
    p.R.r[4] = { src_td, dst_td, w_td, E_ww + E_wt + E_tt + E_wd, BUK_TD, 5, 31 };
    p.Etot = E_total;
    p.npb = (E_total + EPB - 1) / EPB;
    p.W_td = W_td; p.W_tt = W_tt; p.W_c = W_causal; p.W_n = W_noise;
    p.W_ww = W_ww; p.W_wt = W_wt; p.W_wd = W_wd;
    p.b_ww = b_ww; p.b_wt = b_wt; p.b_wd = b_wd; p.b_td = b_td; p.b_tt = b_tt;
    p.cur = cur; p.edataP = edataP;
    p.fw16 = fw16; p.hw16 = hw16; p.wtd16 = wtd16; p.wtt16 = wtt16;
    p.Wtg_ww = Wtg_ww; p.Wtg_wt = Wtg_wt; p.Wtg_wd = Wtg_wd;
    p.Sb2 = Sb2; p.degf2 = degf2;
    p.h_word = h_word; p.h_topic = h_topic; p.h_doc = h_doc;

    // cursor zeroing via async memset (capture-safe)
    hipMemsetAsync(cur, 0, NBUK * sizeof(int), stream);

    // ---- k1: partition || f2b || mm4+combine || W^T (all independent) ----
    unsigned g1 = (unsigned)(p.npb + NF2B + NMM4C + NWTR);
    prep_part_kernel<<<g1, 256, 0, stream>>>(p);

    // ---- k2: ww reduce+project, tt/td reduce+dump (half-buckets) ----
    phaseA_kernel<<<GA, 256, 0, stream>>>(p);

    // ---- k3: wt/wd reduce+project (+ tt/td cross terms, half-buckets) ----
    phaseB_kernel<<<GB, 256, 0, stream>>>(p);

    (void)n_in; (void)in_sizes; (void)out_size; (void)ws_size;
}